// Round 11
// baseline (232.351 us; speedup 1.0000x reference)
//
#include <hip/hip_runtime.h>
#include <hip/hip_bf16.h>
#include <math.h>

#define E_ 768
#define HID_ 1536
#define SQ_ 1024

typedef unsigned short u16;
using bf16x8 = __attribute__((ext_vector_type(8))) __bf16;
using f32x4  = __attribute__((ext_vector_type(4))) float;

__device__ __forceinline__ u16 f2bf(float f) {
  union { float f; unsigned u; } v; v.f = f;
  unsigned r = v.u + 0x7FFFu + ((v.u >> 16) & 1u);
  return (u16)(r >> 16);
}
__device__ __forceinline__ float bf2f(u16 h) {
  union { unsigned u; float f; } v; v.u = ((unsigned)h) << 16; return v.f;
}
__device__ __forceinline__ float gelu_f(float x) {
  return 0.5f * x * (1.0f + erff(x * 0.70710678118654752f));
}

#define GLDS16(gp, sp) __builtin_amdgcn_global_load_lds( \
    (__attribute__((address_space(1))) const void*)(const void*)(gp), \
    (__attribute__((address_space(3))) void*)(void*)(sp), 16, 0, 0)

// ---- prep+rowsum merged: blocks <6144 cast x->bf16; 6144-6719 transpose W1/W2;
// ---- blocks >=6720 run rowsum reading x as f32 (independent inputs -> no hazard)
__global__ void prep_kernel(const float* __restrict__ x, const float* __restrict__ W1,
                            const float* __restrict__ W2, u16* __restrict__ xb,
                            u16* __restrict__ W1T, u16* __restrict__ W2T,
                            float* __restrict__ Rp, float* __restrict__ Y) {
  __shared__ float T[64 * 65];
  int bid = blockIdx.x, t = threadIdx.x;
  if (bid >= 6720) {                      // ---- rowsum section (384 blocks)
    int rb = bid - 6720;                  // r(96)*4 + c
    int r = rb >> 2, c = rb & 3;
    int b = r / 12, n = r % 12;
    if (rb == 0) {
#pragma unroll
      for (int i = 0; i < 24; ++i) Y[t + i * 256] = 0.f;   // zero Y (6144 floats)
    }
    int u0 = n << 10;
    int s_lo = u0 / 12;
    int s_hi = (u0 + 1023) / 12;
    int cnt = s_hi - s_lo + 1;
    int cs = s_lo + (cnt * c) / 4;
    int ce = s_lo + (cnt * (c + 1)) / 4;
    float acc[12][3];
#pragma unroll
    for (int g = 0; g < 12; ++g)
      for (int q = 0; q < 3; ++q) acc[g][q] = 0.f;
    const float* xp = x + (size_t)b * SQ_ * E_;
    for (int s = cs; s < ce; ++s) {
      float v0 = xp[(size_t)s * E_ + t];
      float v1 = xp[(size_t)s * E_ + t + 256];
      float v2 = xp[(size_t)s * E_ + t + 512];
      int du = 12 * s - u0;
#pragma unroll
      for (int g = 0; g < 12; ++g) {
        int u = du + g;
        if (u >= 0 && u < 1024) { acc[g][0] += v0; acc[g][1] += v1; acc[g][2] += v2; }
      }
    }
    float* Rr = Rp + (size_t)rb * 9216;
#pragma unroll
    for (int g = 0; g < 12; ++g) {
      Rr[g * 768 + t]       = acc[g][0];
      Rr[g * 768 + t + 256] = acc[g][1];
      Rr[g * 768 + t + 512] = acc[g][2];
    }
    return;
  }
  if (bid < 6144) {                       // x: 6144*1024 = 6291456 elems
    int base = bid * 1024 + t * 4;
    const float4 v = *reinterpret_cast<const float4*>(x + base);
    ushort4 o; o.x = f2bf(v.x); o.y = f2bf(v.y); o.z = f2bf(v.z); o.w = f2bf(v.w);
    *reinterpret_cast<ushort4*>(xb + base) = o;
    return;
  }
  const float* in; u16* out; int R_in, C_in, rt, ct;
  if (bid < 6432) {                       // W1 (768 x 1536) -> W1T (1536 x 768)
    int b2 = bid - 6144; in = W1; out = W1T; R_in = 768; C_in = 1536;
    rt = b2 / 24; ct = b2 % 24;
  } else {                                // W2 (1536 x 768) -> W2T (768 x 1536)
    int b3 = bid - 6432; in = W2; out = W2T; R_in = 1536; C_in = 768;
    rt = b3 / 12; ct = b3 % 12;
  }
  int r0 = rt << 6, c0 = ct << 6;
  int tr = t >> 4, tc4 = (t & 15) << 2;
#pragma unroll
  for (int i = 0; i < 4; ++i) {
    int row = tr + (i << 4);
    const float4 v = *reinterpret_cast<const float4*>(in + (size_t)(r0 + row) * C_in + c0 + tc4);
    T[row * 65 + tc4 + 0] = v.x;
    T[row * 65 + tc4 + 1] = v.y;
    T[row * 65 + tc4 + 2] = v.z;
    T[row * 65 + tc4 + 3] = v.w;
  }
  __syncthreads();
#pragma unroll
  for (int i = 0; i < 4; ++i) {
    int orow = tr + (i << 4);
    ushort4 o;
    o.x = f2bf(T[(tc4 + 0) * 65 + orow]);
    o.y = f2bf(T[(tc4 + 1) * 65 + orow]);
    o.z = f2bf(T[(tc4 + 2) * 65 + orow]);
    o.w = f2bf(T[(tc4 + 3) * 65 + orow]);
    *reinterpret_cast<ushort4*>(out + (size_t)(c0 + orow) * R_in + r0 + tc4) = o;
  }
}

// ---- yfin (ygemm+ysum fused): block (r, jq) handles j-slice [jq*192, +192) -----
__global__ __launch_bounds__(256, 4) void yfin_kernel(
    const float* __restrict__ Rp, const float* __restrict__ Wv,
    float* __restrict__ Y) {
  int bid = blockIdx.x;            // 384 = r(96)*4 + jq
  int r = bid >> 2, jq = bid & 3;
  int t = threadIdx.x;
  __shared__ float Ls[12 * 192];   // 9,216 B
  __shared__ float red[4][12][64]; // 12,288 B
  const float* Rb = Rp + (size_t)r * 4 * 9216 + jq * 192;
  for (int i = t; i < 576; i += 256) {
    int g = i / 48, off = (i % 48) << 2;
    const float* p = Rb + g * 768 + off;
    float4 v0 = *reinterpret_cast<const float4*>(p);
    float4 v1 = *reinterpret_cast<const float4*>(p + 9216);
    float4 v2 = *reinterpret_cast<const float4*>(p + 18432);
    float4 v3 = *reinterpret_cast<const float4*>(p + 27648);
    float4 s4;
    s4.x = (v0.x + v1.x) + (v2.x + v3.x);
    s4.y = (v0.y + v1.y) + (v2.y + v3.y);
    s4.z = (v0.z + v1.z) + (v2.z + v3.z);
    s4.w = (v0.w + v1.w) + (v2.w + v3.w);
    *reinterpret_cast<float4*>(&Ls[g * 192 + off]) = s4;
  }
  __syncthreads();
  int d = t & 63, sub = t >> 6;
  float part[12];
#pragma unroll
  for (int g = 0; g < 12; ++g) part[g] = 0.f;
  int jl0 = sub * 48;
  const float* wp = Wv + (size_t)(jq * 192) * 768 + d;
  for (int jj = 0; jj < 48; ++jj) {
    int jl = jl0 + jj;
    const float* wj = wp + (size_t)jl * 768;
#pragma unroll
    for (int g = 0; g < 12; ++g)
      part[g] += Ls[g * 192 + jl] * wj[g * 64];
  }
#pragma unroll
  for (int g = 0; g < 12; ++g) red[sub][g][d] = part[g];
  __syncthreads();
  if (t < 64) {
    float s = 0.f;
#pragma unroll
    for (int su = 0; su < 4; ++su)
#pragma unroll
      for (int g = 0; g < 12; ++g) s += red[su][g][t];
    atomicAdd(&Y[r * 64 + t], s);
  }
}

// ------- c1 (LN1 fused): L = LN(Y[b,:]); C1[b,:] = b1 + L @ W1 ------------------
__global__ void c1_kernel(const float* __restrict__ Y, const float* __restrict__ g1,
                          const float* __restrict__ be1, const float* __restrict__ W1,
                          const float* __restrict__ b1, float* __restrict__ C1) {
  int bid = blockIdx.x;          // 384 = b(8)*48
  int b = bid / 48, c = bid % 48;
  int t = threadIdx.x;
  __shared__ float Ls[768];
  __shared__ float red[8][32];
  __shared__ float red2[8];
  float y0 = Y[b * 768 + t];
  float y1 = Y[b * 768 + t + 256];
  float y2 = Y[b * 768 + t + 512];
  float s = y0 + y1 + y2;
  float sq = y0 * y0 + y1 * y1 + y2 * y2;
#pragma unroll
  for (int o = 32; o > 0; o >>= 1) { s += __shfl_down(s, o, 64); sq += __shfl_down(sq, o, 64); }
  if ((t & 63) == 0) { red2[(t >> 6) * 2] = s; red2[(t >> 6) * 2 + 1] = sq; }
  __syncthreads();
  s  = red2[0] + red2[2] + red2[4] + red2[6];
  sq = red2[1] + red2[3] + red2[5] + red2[7];
  float mu = s * (1.f / 768.f);
  float var = sq * (1.f / 768.f) - mu * mu;
  float rsv = rsqrtf(var + 1e-5f);
  Ls[t]       = (y0 - mu) * rsv * g1[t]       + be1[t];
  Ls[t + 256] = (y1 - mu) * rsv * g1[t + 256] + be1[t + 256];
  Ls[t + 512] = (y2 - mu) * rsv * g1[t + 512] + be1[t + 512];
  __syncthreads();
  int tc = t & 31, ts = t >> 5;
  int n = c * 32 + tc;
  float acc = 0.f;
  int j0 = ts * 96;
#pragma unroll 4
  for (int j = j0; j < j0 + 96; ++j) acc += Ls[j] * W1[(size_t)j * HID_ + n];
  red[ts][tc] = acc;
  __syncthreads();
  if (ts == 0) {
    float sv = b1[n];
#pragma unroll
    for (int k = 0; k < 8; ++k) sv += red[k][tc];
    C1[b * HID_ + n] = sv;
  }
}

// ---- bf16 MFMA GEMM v5: faithful m201 8-phase port. 256x256 tile, BK=64,
// 8 waves (2M x 4N, 128x64 out/wave), 128 KiB dbuf LDS (buf0=even kt, buf1=odd).
// Per phase: {ds_read subtile || stage ONE half-tile (2 gloads/thr)} -> s_barrier
// -> setprio(1)+16 MFMA+setprio(0) -> s_barrier. Counted vmcnt(2) ONLY at phases
// 4 and 8 (just-issued half stays in flight); vmcnt(0) never in steady state.
// Hazards: buf reads complete (barrier) before any stage targets it; every vmcnt
// precedes a shared barrier so all waves' stages landed before any wave reads.
// Both-sides XOR swizzle identical to proven BK=64 kernels (conflict-free).
// MODE 0 (gemm1): K=768, bias=C1[batch], GELU, bf16 out0. grid 192 (32Mx6N).
// MODE 1 (gemm2): split-K2, no bias/GELU; partial to (kk==0?out0:out1). grid 192.
template <int MODE>
__global__ __launch_bounds__(512, 2) void gemm_bt_kernel(
    const u16* __restrict__ A, const u16* __restrict__ BT,
    const float* __restrict__ bias, void* __restrict__ out0, void* __restrict__ out1,
    int N, int lda, int ldb) {
  __shared__ __align__(16) u16 As0[256 * 64], As1[256 * 64];  // 32 KB each
  __shared__ __align__(16) u16 Bs0[256 * 64], Bs1[256 * 64];
  int bid = blockIdx.x;
  int xcd = bid & 7, idx = bid >> 3;            // idx 0..23
  int mtile, ntile, k_off, kk = 0;
  if (MODE == 0) { mtile = xcd * 4 + idx / 6; ntile = idx % 6; k_off = 0; }
  else           { kk = idx / 12; int rem = idx % 12; mtile = xcd * 4 + rem / 3; ntile = rem % 3; k_off = kk * 768; }
  int bm = mtile << 8, bn = ntile << 8;

  int t = threadIdx.x;
  int lane = t & 63, w = t >> 6;                // 8 waves
  int wm = (w >> 2) << 7, wn = (w & 3) << 6;    // 2M x 4N
  int quad = lane >> 4, l16 = lane & 15;
  f32x4 acc[8][4] = {};
  bf16x8 af[4][2], bf[4][2];

  // precomputed per-thread staging offsets (2 chunks/thread per half-tile)
  int ci0 = t, ci1 = t + 512;
  int sr0 = ci0 >> 3, sr1 = ci1 >> 3;
  size_t aof0 = (size_t)sr0 * lda + ((((ci0 & 7) ^ (sr0 & 7))) << 3);
  size_t aof1 = (size_t)sr1 * lda + ((((ci1 & 7) ^ (sr1 & 7))) << 3);
  size_t bof0 = (size_t)sr0 * ldb + ((((ci0 & 7) ^ (sr0 & 7))) << 3);
  size_t bof1 = (size_t)sr1 * ldb + ((((ci1 & 7) ^ (sr1 & 7))) << 3);
  int ldso0 = ci0 << 3, ldso1 = ci1 << 3;

  const u16* Ab = A + (size_t)bm * lda + k_off;        // rows bm..      (half0)
  const u16* Ab2 = Ab + (size_t)128 * lda;             // rows bm+128..  (half1)
  const u16* Bb = BT + (size_t)bn * ldb + k_off;
  const u16* Bb2 = Bb + (size_t)128 * ldb;

  auto STG_A = [&](u16* dst, const u16* src) {
    GLDS16(src + aof0, dst + ldso0);
    GLDS16(src + aof1, dst + ldso1);
  };
  auto STG_B = [&](u16* dst, const u16* src) {
    GLDS16(src + bof0, dst + ldso0);
    GLDS16(src + bof1, dst + ldso1);
  };
  auto LDA = [&](const u16* as, int m0t) {             // af <- 4 m-tiles x 2 ks
#pragma unroll
    for (int mt = 0; mt < 4; ++mt)
#pragma unroll
      for (int ks = 0; ks < 2; ++ks) {
        int row = wm + ((m0t + mt) << 4) + l16;
        int kc = (ks << 2) + quad;
        af[mt][ks] = *reinterpret_cast<const bf16x8*>(as + row * 64 + ((kc ^ (row & 7)) << 3));
      }
  };
  auto LDB = [&](const u16* bs, int n0t) {             // bf[n0t..n0t+1] x 2 ks
#pragma unroll
    for (int nt = 0; nt < 2; ++nt)
#pragma unroll
      for (int ks = 0; ks < 2; ++ks) {
        int row = wn + ((n0t + nt) << 4) + l16;
        int kc = (ks << 2) + quad;
        bf[n0t + nt][ks] = *reinterpret_cast<const bf16x8*>(bs + row * 64 + ((kc ^ (row & 7)) << 3));
      }
  };
  auto MM = [&](int ma, int na) {                      // 16 MFMA quadrant
    __builtin_amdgcn_s_setprio(1);
#pragma unroll
    for (int mt = 0; mt < 4; ++mt)
#pragma unroll
      for (int nt = 0; nt < 2; ++nt)
#pragma unroll
        for (int ks = 0; ks < 2; ++ks)
          acc[ma + mt][na + nt] =
              __builtin_amdgcn_mfma_f32_16x16x32_bf16(af[mt][ks], bf[na + nt][ks], acc[ma + mt][na + nt], 0, 0, 0);
    __builtin_amdgcn_s_setprio(0);
  };

  // ---- prologue: stage kt0 fully (4 halves) + kt1 half0; wait kt0 landed ------
  STG_A(As0, Ab);          STG_A(As0 + 8192, Ab2);
  STG_B(Bs0, Bb);          STG_B(Bs0 + 8192, Bb2);
  STG_A(As1, Ab + 64);
  asm volatile("s_waitcnt vmcnt(2)" ::: "memory");
  __builtin_amdgcn_s_barrier();

  for (int it = 0; it < 6; ++it) {
    int c1o = (2 * it + 1) << 6;                       // col of kt1
    int c2o = (2 * it + 2) << 6;                       // col of kt0+2
    int c3o = (2 * it + 3) << 6;                       // col of kt1+2
    bool st = (it < 5);
    // ph1: read buf0 (A m0-3, B n0-1); stage kt1 h1 (A half1 -> As1+8192)
    LDA(As0, 0); LDB(Bs0, 0);
    STG_A(As1 + 8192, Ab2 + c1o);
    __builtin_amdgcn_s_barrier();
    MM(0, 0);
    __builtin_amdgcn_s_barrier();
    // ph2: read B n2-3; stage kt1 h2 (B half0 -> Bs1)
    LDB(Bs0, 2);
    STG_B(Bs1, Bb + c1o);
    __builtin_amdgcn_s_barrier();
    MM(0, 2);
    __builtin_amdgcn_s_barrier();
    // ph3: read A m4-7; stage kt1 h3 (B half1 -> Bs1+8192)
    LDA(As0, 4);
    STG_B(Bs1 + 8192, Bb2 + c1o);
    __builtin_amdgcn_s_barrier();
    MM(4, 2);
    __builtin_amdgcn_s_barrier();
    // ph4: no reads (reuse af m4-7, bf n0-1); stage kt0+2 h0 (A half0 -> As0)
    if (st) STG_A(As0, Ab + c2o);
    __builtin_amdgcn_s_barrier();
    MM(4, 0);
    if (st) asm volatile("s_waitcnt vmcnt(2)" ::: "memory");
    else    asm volatile("s_waitcnt vmcnt(0)" ::: "memory");
    __builtin_amdgcn_s_barrier();
    // ph5: read buf1 (A m0-3, B n0-1); stage kt0+2 h1
    LDA(As1, 0); LDB(Bs1, 0);
    if (st) STG_A(As0 + 8192, Ab2 + c2o);
    __builtin_amdgcn_s_barrier();
    MM(0, 0);
    __builtin_amdgcn_s_barrier();
    // ph6: read B n2-3; stage kt0+2 h2
    LDB(Bs1, 2);
    if (st) STG_B(Bs0, Bb + c2o);
    __builtin_amdgcn_s_barrier();
    MM(0, 2);
    __builtin_amdgcn_s_barrier();
    // ph7: read A m4-7; stage kt0+2 h3
    LDA(As1, 4);
    if (st) STG_B(Bs0 + 8192, Bb2 + c2o);
    __builtin_amdgcn_s_barrier();
    MM(4, 2);
    __builtin_amdgcn_s_barrier();
    // ph8: no reads; stage kt1+2 h0 (A half0 -> As1)
    if (st) STG_A(As1, Ab + c3o);
    __builtin_amdgcn_s_barrier();
    MM(4, 0);
    if (st) asm volatile("s_waitcnt vmcnt(2)" ::: "memory");
    __builtin_amdgcn_s_barrier();
  }

#pragma unroll
  for (int mt = 0; mt < 8; ++mt) {
    int row0 = bm + wm + (mt << 4) + (quad << 2);
#pragma unroll
    for (int nt = 0; nt < 4; ++nt) {
      int col = bn + wn + (nt << 4) + l16;
      float bv = (MODE == 0) ? bias[(bm >> 10) * N + col] : 0.f;
#pragma unroll
      for (int rr = 0; rr < 4; ++rr) {
        float v = acc[mt][nt][rr] + bv;
        size_t idxo = (size_t)(row0 + rr) * N + col;
        if (MODE == 0)       ((u16*)out0)[idxo] = f2bf(gelu_f(v));
        else if (kk == 0)    ((u16*)out0)[idxo] = f2bf(v);
        else                 ((u16*)out1)[idxo] = f2bf(v);
      }
    }
  }
}

// ------- LN2 (192 threads, all active): m = GELU(p0+p1+b2); out = x + LN(m) -----
__global__ void ln2_kernel(const u16* __restrict__ p0, const u16* __restrict__ p1,
                           const float* __restrict__ x, const float* __restrict__ b2,
                           const float* __restrict__ g2, const float* __restrict__ be2,
                           float* __restrict__ out) {
  int row = blockIdx.x, t = threadIdx.x;
  int e = t << 2;
  ushort4 pa = *reinterpret_cast<const ushort4*>(p0 + (size_t)row * 768 + e);
  ushort4 pb = *reinterpret_cast<const ushort4*>(p1 + (size_t)row * 768 + e);
  float4 bb = *reinterpret_cast<const float4*>(b2 + e);
  float v0 = gelu_f(bf2f(pa.x) + bf2f(pb.x) + bb.x);
  float v1 = gelu_f(bf2f(pa.y) + bf2f(pb.y) + bb.y);
  float v2 = gelu_f(bf2f(pa.z) + bf2f(pb.z) + bb.z);
  float v3 = gelu_f(bf2f(pa.w) + bf2f(pb.w) + bb.w);
  float s = (v0 + v1) + (v2 + v3);
  float sq = (v0 * v0 + v1 * v1) + (v2 * v2 + v3 * v3);
  __shared__ float red[8];
#pragma unroll
  for (int o = 32; o > 0; o >>= 1) { s += __shfl_down(s, o, 64); sq += __shfl_down(sq, o, 64); }
  if ((t & 63) == 0) { red[(t >> 6) * 2] = s; red[(t >> 6) * 2 + 1] = sq; }
  __syncthreads();
  s  = red[0] + red[2] + red[4];
  sq = red[1] + red[3] + red[5];
  float mu = s * (1.f / 768.f);
  float var = sq * (1.f / 768.f) - mu * mu;
  float rs = rsqrtf(var + 1e-5f);
  float4 gg = *reinterpret_cast<const float4*>(g2 + e);
  float4 be = *reinterpret_cast<const float4*>(be2 + e);
  float4 xx = *reinterpret_cast<const float4*>(x + (size_t)row * 768 + e);
  float4 o;
  o.x = xx.x + (v0 - mu) * rs * gg.x + be.x;
  o.y = xx.y + (v1 - mu) * rs * gg.y + be.y;
  o.z = xx.z + (v2 - mu) * rs * gg.z + be.z;
  o.w = xx.w + (v3 - mu) * rs * gg.w + be.w;
  *reinterpret_cast<float4*>(out + (size_t)row * 768 + e) = o;
}

extern "C" void kernel_launch(void* const* d_in, const int* in_sizes, int n_in,
                              void* d_out, int out_size, void* d_ws, size_t ws_size,
                              hipStream_t stream) {
  const float* x   = (const float*)d_in[0];
  // d_in[1]=Wq, d_in[2]=Wk are mathematically dead (softmax rows sum to 1).
  const float* Wv  = (const float*)d_in[3];
  const float* W1  = (const float*)d_in[4];
  const float* b1  = (const float*)d_in[5];
  const float* W2  = (const float*)d_in[6];
  const float* b2  = (const float*)d_in[7];
  const float* g1  = (const float*)d_in[8];
  const float* be1 = (const float*)d_in[9];
  const float* g2  = (const float*)d_in[10];
  const float* be2 = (const float*)d_in[11];
  float* out = (float*)d_out;

  char* ws = (char*)d_ws;
  u16*   xb  = (u16*)(ws);                       // 12,582,912 B  (8192x768 bf16)
  u16*   W1T = (u16*)(ws + 12582912);            //  2,359,296 B  (1536x768 bf16)
  u16*   W2T = (u16*)(ws + 14942208);            //  2,359,296 B  (768x1536 bf16)
  u16*   h   = (u16*)(ws + 17301504);            // 25,165,824 B  (8192x1536 bf16)
  // Rp ALIASES h: Rp consumed by yfin before gemm1 writes h (same stream).
  float* Rp  = (float*)(ws + 17301504);          // 14,155,776 B  (384x9216 f32)
  float* Y   = (float*)(ws + 44826624);          //     24,576 B  (8x768 f32)
  float* C1  = (float*)(ws + 44875776);          //     49,152 B  (8x1536 f32)
  u16*   m0  = (u16*)(ws + 44924928);            // 12,582,912 B  (8192x768 bf16) gemm2 kk=0 partial
  // p1 ALIASES xb: xb dead after gemm1; gemm2 half-1 partial (bf16) lives there.
  u16*   p1  = xb;

  prep_kernel<<<7104, 256, 0, stream>>>(x, W1, W2, xb, W1T, W2T, Rp, Y);
  yfin_kernel<<<384, 256, 0, stream>>>(Rp, Wv, Y);
  c1_kernel<<<384, 256, 0, stream>>>(Y, g1, be1, W1, b1, C1);
  gemm_bt_kernel<0><<<192, 512, 0, stream>>>(xb, W1T, C1, (void*)h, nullptr, 1536, 768, 768);
  gemm_bt_kernel<1><<<192, 512, 0, stream>>>(h, W2T, nullptr, (void*)m0, (void*)p1, 768, 1536, 1536);
  ln2_kernel<<<8192, 192, 0, stream>>>(m0, p1, x, b2, g2, be2, out);
}

// Round 12
// 214.952 us; speedup vs baseline: 1.0809x; 1.0809x over previous
//
#include <hip/hip_runtime.h>
#include <hip/hip_bf16.h>
#include <math.h>

#define E_ 768
#define HID_ 1536
#define SQ_ 1024

typedef unsigned short u16;
using bf16x8 = __attribute__((ext_vector_type(8))) __bf16;
using f32x4  = __attribute__((ext_vector_type(4))) float;

__device__ __forceinline__ u16 f2bf(float f) {
  union { float f; unsigned u; } v; v.f = f;
  unsigned r = v.u + 0x7FFFu + ((v.u >> 16) & 1u);
  return (u16)(r >> 16);
}
__device__ __forceinline__ float bf2f(u16 h) {
  union { unsigned u; float f; } v; v.u = ((unsigned)h) << 16; return v.f;
}
__device__ __forceinline__ float gelu_f(float x) {
  return 0.5f * x * (1.0f + erff(x * 0.70710678118654752f));
}

#define GLDS16(gp, sp) __builtin_amdgcn_global_load_lds( \
    (__attribute__((address_space(1))) const void*)(const void*)(gp), \
    (__attribute__((address_space(3))) void*)(void*)(sp), 16, 0, 0)

// ---- prep+rowsum merged: blocks <6144 cast x->bf16; 6144-6719 transpose W1/W2;
// ---- blocks >=6720 run rowsum reading x as f32 (independent inputs -> no hazard)
__global__ void prep_kernel(const float* __restrict__ x, const float* __restrict__ W1,
                            const float* __restrict__ W2, u16* __restrict__ xb,
                            u16* __restrict__ W1T, u16* __restrict__ W2T,
                            float* __restrict__ Rp, float* __restrict__ Y) {
  __shared__ float T[64 * 65];
  int bid = blockIdx.x, t = threadIdx.x;
  if (bid >= 6720) {                      // ---- rowsum section (384 blocks)
    int rb = bid - 6720;                  // r(96)*4 + c
    int r = rb >> 2, c = rb & 3;
    int b = r / 12, n = r % 12;
    if (rb == 0) {
#pragma unroll
      for (int i = 0; i < 24; ++i) Y[t + i * 256] = 0.f;   // zero Y (6144 floats)
    }
    int u0 = n << 10;
    int s_lo = u0 / 12;
    int s_hi = (u0 + 1023) / 12;
    int cnt = s_hi - s_lo + 1;
    int cs = s_lo + (cnt * c) / 4;
    int ce = s_lo + (cnt * (c + 1)) / 4;
    float acc[12][3];
#pragma unroll
    for (int g = 0; g < 12; ++g)
      for (int q = 0; q < 3; ++q) acc[g][q] = 0.f;
    const float* xp = x + (size_t)b * SQ_ * E_;
    for (int s = cs; s < ce; ++s) {
      float v0 = xp[(size_t)s * E_ + t];
      float v1 = xp[(size_t)s * E_ + t + 256];
      float v2 = xp[(size_t)s * E_ + t + 512];
      int du = 12 * s - u0;
#pragma unroll
      for (int g = 0; g < 12; ++g) {
        int u = du + g;
        if (u >= 0 && u < 1024) { acc[g][0] += v0; acc[g][1] += v1; acc[g][2] += v2; }
      }
    }
    float* Rr = Rp + (size_t)rb * 9216;
#pragma unroll
    for (int g = 0; g < 12; ++g) {
      Rr[g * 768 + t]       = acc[g][0];
      Rr[g * 768 + t + 256] = acc[g][1];
      Rr[g * 768 + t + 512] = acc[g][2];
    }
    return;
  }
  if (bid < 6144) {                       // x: 6144*1024 = 6291456 elems
    int base = bid * 1024 + t * 4;
    const float4 v = *reinterpret_cast<const float4*>(x + base);
    ushort4 o; o.x = f2bf(v.x); o.y = f2bf(v.y); o.z = f2bf(v.z); o.w = f2bf(v.w);
    *reinterpret_cast<ushort4*>(xb + base) = o;
    return;
  }
  const float* in; u16* out; int R_in, C_in, rt, ct;
  if (bid < 6432) {                       // W1 (768 x 1536) -> W1T (1536 x 768)
    int b2 = bid - 6144; in = W1; out = W1T; R_in = 768; C_in = 1536;
    rt = b2 / 24; ct = b2 % 24;
  } else {                                // W2 (1536 x 768) -> W2T (768 x 1536)
    int b3 = bid - 6432; in = W2; out = W2T; R_in = 1536; C_in = 768;
    rt = b3 / 12; ct = b3 % 12;
  }
  int r0 = rt << 6, c0 = ct << 6;
  int tr = t >> 4, tc4 = (t & 15) << 2;
#pragma unroll
  for (int i = 0; i < 4; ++i) {
    int row = tr + (i << 4);
    const float4 v = *reinterpret_cast<const float4*>(in + (size_t)(r0 + row) * C_in + c0 + tc4);
    T[row * 65 + tc4 + 0] = v.x;
    T[row * 65 + tc4 + 1] = v.y;
    T[row * 65 + tc4 + 2] = v.z;
    T[row * 65 + tc4 + 3] = v.w;
  }
  __syncthreads();
#pragma unroll
  for (int i = 0; i < 4; ++i) {
    int orow = tr + (i << 4);
    ushort4 o;
    o.x = f2bf(T[(tc4 + 0) * 65 + orow]);
    o.y = f2bf(T[(tc4 + 1) * 65 + orow]);
    o.z = f2bf(T[(tc4 + 2) * 65 + orow]);
    o.w = f2bf(T[(tc4 + 3) * 65 + orow]);
    *reinterpret_cast<ushort4*>(out + (size_t)(c0 + orow) * R_in + r0 + tc4) = o;
  }
}

// ---- yfin (ygemm+ysum fused): block (r, jq) handles j-slice [jq*192, +192) -----
__global__ __launch_bounds__(256, 4) void yfin_kernel(
    const float* __restrict__ Rp, const float* __restrict__ Wv,
    float* __restrict__ Y) {
  int bid = blockIdx.x;            // 384 = r(96)*4 + jq
  int r = bid >> 2, jq = bid & 3;
  int t = threadIdx.x;
  __shared__ float Ls[12 * 192];   // 9,216 B
  __shared__ float red[4][12][64]; // 12,288 B
  const float* Rb = Rp + (size_t)r * 4 * 9216 + jq * 192;
  for (int i = t; i < 576; i += 256) {
    int g = i / 48, off = (i % 48) << 2;
    const float* p = Rb + g * 768 + off;
    float4 v0 = *reinterpret_cast<const float4*>(p);
    float4 v1 = *reinterpret_cast<const float4*>(p + 9216);
    float4 v2 = *reinterpret_cast<const float4*>(p + 18432);
    float4 v3 = *reinterpret_cast<const float4*>(p + 27648);
    float4 s4;
    s4.x = (v0.x + v1.x) + (v2.x + v3.x);
    s4.y = (v0.y + v1.y) + (v2.y + v3.y);
    s4.z = (v0.z + v1.z) + (v2.z + v3.z);
    s4.w = (v0.w + v1.w) + (v2.w + v3.w);
    *reinterpret_cast<float4*>(&Ls[g * 192 + off]) = s4;
  }
  __syncthreads();
  int d = t & 63, sub = t >> 6;
  float part[12];
#pragma unroll
  for (int g = 0; g < 12; ++g) part[g] = 0.f;
  int jl0 = sub * 48;
  const float* wp = Wv + (size_t)(jq * 192) * 768 + d;
  for (int jj = 0; jj < 48; ++jj) {
    int jl = jl0 + jj;
    const float* wj = wp + (size_t)jl * 768;
#pragma unroll
    for (int g = 0; g < 12; ++g)
      part[g] += Ls[g * 192 + jl] * wj[g * 64];
  }
#pragma unroll
  for (int g = 0; g < 12; ++g) red[sub][g][d] = part[g];
  __syncthreads();
  if (t < 64) {
    float s = 0.f;
#pragma unroll
    for (int su = 0; su < 4; ++su)
#pragma unroll
      for (int g = 0; g < 12; ++g) s += red[su][g][t];
    atomicAdd(&Y[r * 64 + t], s);
  }
}

// ------- c1 (LN1 fused): L = LN(Y[b,:]); C1[b,:] = b1 + L @ W1 ------------------
__global__ void c1_kernel(const float* __restrict__ Y, const float* __restrict__ g1,
                          const float* __restrict__ be1, const float* __restrict__ W1,
                          const float* __restrict__ b1, float* __restrict__ C1) {
  int bid = blockIdx.x;          // 384 = b(8)*48
  int b = bid / 48, c = bid % 48;
  int t = threadIdx.x;
  __shared__ float Ls[768];
  __shared__ float red[8][32];
  __shared__ float red2[8];
  float y0 = Y[b * 768 + t];
  float y1 = Y[b * 768 + t + 256];
  float y2 = Y[b * 768 + t + 512];
  float s = y0 + y1 + y2;
  float sq = y0 * y0 + y1 * y1 + y2 * y2;
#pragma unroll
  for (int o = 32; o > 0; o >>= 1) { s += __shfl_down(s, o, 64); sq += __shfl_down(sq, o, 64); }
  if ((t & 63) == 0) { red2[(t >> 6) * 2] = s; red2[(t >> 6) * 2 + 1] = sq; }
  __syncthreads();
  s  = red2[0] + red2[2] + red2[4] + red2[6];
  sq = red2[1] + red2[3] + red2[5] + red2[7];
  float mu = s * (1.f / 768.f);
  float var = sq * (1.f / 768.f) - mu * mu;
  float rsv = rsqrtf(var + 1e-5f);
  Ls[t]       = (y0 - mu) * rsv * g1[t]       + be1[t];
  Ls[t + 256] = (y1 - mu) * rsv * g1[t + 256] + be1[t + 256];
  Ls[t + 512] = (y2 - mu) * rsv * g1[t + 512] + be1[t + 512];
  __syncthreads();
  int tc = t & 31, ts = t >> 5;
  int n = c * 32 + tc;
  float acc = 0.f;
  int j0 = ts * 96;
#pragma unroll 4
  for (int j = j0; j < j0 + 96; ++j) acc += Ls[j] * W1[(size_t)j * HID_ + n];
  red[ts][tc] = acc;
  __syncthreads();
  if (ts == 0) {
    float sv = b1[n];
#pragma unroll
    for (int k = 0; k < 8; ++k) sv += red[k][tc];
    C1[b * HID_ + n] = sv;
  }
}

// ---------------- bf16 MFMA GEMM, XCD-swizzled flat grid (measured-best form) ---
// Serial stage -> vmcnt(0) -> compute per K-tile; 32 KB LDS -> ~3 blocks/CU of
// implicit TLP. Seven restructures (4-phase, 2-phase dbuf, inline-bias, small-
// tile TLP, BK=128, 8-phase counted-vmcnt) all measured 41-54 us vs this at 41.
// MODE 0 (gemm1): full K=768, bias=C1[batch], GELU, bf16 out0. grid 768.
// MODE 1 (gemm2): split-K2, no bias/GELU; bf16 partial to (kk==0?out0:out1).
template <int MODE>
__global__ __launch_bounds__(256, 2) void gemm_bt_kernel(
    const u16* __restrict__ A, const u16* __restrict__ BT,
    const float* __restrict__ bias, void* __restrict__ out0, void* __restrict__ out1,
    int N, int lda, int ldb) {
  __shared__ __align__(16) u16 As[128 * 64];
  __shared__ __align__(16) u16 Bs[128 * 64];
  int bid = blockIdx.x;
  int xcd = bid & 7, idx = bid >> 3;
  int mloc, n_, k_off, kk = 0;
  if (MODE == 0) { mloc = idx / 12; n_ = idx % 12; k_off = 0; }
  else           { kk = idx / 48; int rem = idx % 48; mloc = rem / 6; n_ = rem % 6; k_off = kk * 768; }
  int bm = (xcd * 8 + mloc) << 7, bn = n_ << 7;

  int t = threadIdx.x;
  int lane = t & 63, w = t >> 6;
  int wm = (w >> 1) << 6, wn = (w & 1) << 6;
  int quad = lane >> 4, l16 = lane & 15;
  f32x4 acc[4][4] = {};

  for (int k0 = 0; k0 < 768; k0 += 64) {
    __syncthreads();
#pragma unroll
    for (int i = 0; i < 4; ++i) {
      int ci = t + (i << 8);           // chunk index 0..1023
      int r = ci >> 3, csw = ci & 7;   // LDS slot (r, csw)
      int kc = csw ^ (r & 7);          // XOR swizzle
      const u16* ga = A + (size_t)(bm + r) * lda + k_off + k0 + (kc << 3);
      GLDS16(ga, As + ci * 8);
      const u16* gb = BT + (size_t)(bn + r) * ldb + k_off + k0 + (kc << 3);
      GLDS16(gb, Bs + ci * 8);
    }
    __builtin_amdgcn_s_waitcnt(0);
    __syncthreads();
#pragma unroll
    for (int ks = 0; ks < 2; ++ks) {
      bf16x8 af[4], bf[4];
      int kc = (ks << 2) + quad;
#pragma unroll
      for (int mt = 0; mt < 4; ++mt) {
        int row = wm + (mt << 4) + l16;
        af[mt] = *reinterpret_cast<const bf16x8*>(As + row * 64 + ((kc ^ (row & 7)) << 3));
      }
#pragma unroll
      for (int nt = 0; nt < 4; ++nt) {
        int row = wn + (nt << 4) + l16;
        bf[nt] = *reinterpret_cast<const bf16x8*>(Bs + row * 64 + ((kc ^ (row & 7)) << 3));
      }
#pragma unroll
      for (int mt = 0; mt < 4; ++mt)
#pragma unroll
        for (int nt = 0; nt < 4; ++nt)
          acc[mt][nt] = __builtin_amdgcn_mfma_f32_16x16x32_bf16(af[mt], bf[nt], acc[mt][nt], 0, 0, 0);
    }
  }

#pragma unroll
  for (int mt = 0; mt < 4; ++mt) {
    int row0 = bm + wm + (mt << 4) + (quad << 2);
#pragma unroll
    for (int nt = 0; nt < 4; ++nt) {
      int col = bn + wn + (nt << 4) + l16;
      float bv = (MODE == 0) ? bias[(bm >> 10) * N + col] : 0.f;
#pragma unroll
      for (int rr = 0; rr < 4; ++rr) {
        float v = acc[mt][nt][rr] + bv;
        size_t idxo = (size_t)(row0 + rr) * N + col;
        if (MODE == 0)       ((u16*)out0)[idxo] = f2bf(gelu_f(v));
        else if (kk == 0)    ((u16*)out0)[idxo] = f2bf(v);
        else                 ((u16*)out1)[idxo] = f2bf(v);
      }
    }
  }
}

// ------- LN2 (192 threads, all active): m = GELU(p0+p1+b2); out = x + LN(m) -----
__global__ void ln2_kernel(const u16* __restrict__ p0, const u16* __restrict__ p1,
                           const float* __restrict__ x, const float* __restrict__ b2,
                           const float* __restrict__ g2, const float* __restrict__ be2,
                           float* __restrict__ out) {
  int row = blockIdx.x, t = threadIdx.x;
  int e = t << 2;
  ushort4 pa = *reinterpret_cast<const ushort4*>(p0 + (size_t)row * 768 + e);
  ushort4 pb = *reinterpret_cast<const ushort4*>(p1 + (size_t)row * 768 + e);
  float4 bb = *reinterpret_cast<const float4*>(b2 + e);
  float v0 = gelu_f(bf2f(pa.x) + bf2f(pb.x) + bb.x);
  float v1 = gelu_f(bf2f(pa.y) + bf2f(pb.y) + bb.y);
  float v2 = gelu_f(bf2f(pa.z) + bf2f(pb.z) + bb.z);
  float v3 = gelu_f(bf2f(pa.w) + bf2f(pb.w) + bb.w);
  float s = (v0 + v1) + (v2 + v3);
  float sq = (v0 * v0 + v1 * v1) + (v2 * v2 + v3 * v3);
  __shared__ float red[8];
#pragma unroll
  for (int o = 32; o > 0; o >>= 1) { s += __shfl_down(s, o, 64); sq += __shfl_down(sq, o, 64); }
  if ((t & 63) == 0) { red[(t >> 6) * 2] = s; red[(t >> 6) * 2 + 1] = sq; }
  __syncthreads();
  s  = red[0] + red[2] + red[4];
  sq = red[1] + red[3] + red[5];
  float mu = s * (1.f / 768.f);
  float var = sq * (1.f / 768.f) - mu * mu;
  float rs = rsqrtf(var + 1e-5f);
  float4 gg = *reinterpret_cast<const float4*>(g2 + e);
  float4 be = *reinterpret_cast<const float4*>(be2 + e);
  float4 xx = *reinterpret_cast<const float4*>(x + (size_t)row * 768 + e);
  float4 o;
  o.x = xx.x + (v0 - mu) * rs * gg.x + be.x;
  o.y = xx.y + (v1 - mu) * rs * gg.y + be.y;
  o.z = xx.z + (v2 - mu) * rs * gg.z + be.z;
  o.w = xx.w + (v3 - mu) * rs * gg.w + be.w;
  *reinterpret_cast<float4*>(out + (size_t)row * 768 + e) = o;
}

extern "C" void kernel_launch(void* const* d_in, const int* in_sizes, int n_in,
                              void* d_out, int out_size, void* d_ws, size_t ws_size,
                              hipStream_t stream) {
  const float* x   = (const float*)d_in[0];
  // d_in[1]=Wq, d_in[2]=Wk are mathematically dead (softmax rows sum to 1).
  const float* Wv  = (const float*)d_in[3];
  const float* W1  = (const float*)d_in[4];
  const float* b1  = (const float*)d_in[5];
  const float* W2  = (const float*)d_in[6];
  const float* b2  = (const float*)d_in[7];
  const float* g1  = (const float*)d_in[8];
  const float* be1 = (const float*)d_in[9];
  const float* g2  = (const float*)d_in[10];
  const float* be2 = (const float*)d_in[11];
  float* out = (float*)d_out;

  char* ws = (char*)d_ws;
  u16*   xb  = (u16*)(ws);                       // 12,582,912 B  (8192x768 bf16)
  u16*   W1T = (u16*)(ws + 12582912);            //  2,359,296 B  (1536x768 bf16)
  u16*   W2T = (u16*)(ws + 14942208);            //  2,359,296 B  (768x1536 bf16)
  u16*   h   = (u16*)(ws + 17301504);            // 25,165,824 B  (8192x1536 bf16)
  // Rp ALIASES h: Rp consumed by yfin before gemm1 writes h (same stream).
  float* Rp  = (float*)(ws + 17301504);          // 14,155,776 B  (384x9216 f32)
  float* Y   = (float*)(ws + 44826624);          //     24,576 B  (8x768 f32)
  float* C1  = (float*)(ws + 44875776);          //     49,152 B  (8x1536 f32)
  u16*   m0  = (u16*)(ws + 44924928);            // 12,582,912 B  (8192x768 bf16) gemm2 kk=0 partial
  // p1 ALIASES xb: xb dead after gemm1; gemm2 half-1 partial (bf16) lives there.
  u16*   p1  = xb;

  prep_kernel<<<7104, 256, 0, stream>>>(x, W1, W2, xb, W1T, W2T, Rp, Y);
  yfin_kernel<<<384, 256, 0, stream>>>(Rp, Wv, Y);
  c1_kernel<<<384, 256, 0, stream>>>(Y, g1, be1, W1, b1, C1);
  gemm_bt_kernel<0><<<768, 256, 0, stream>>>(xb, W1T, C1, (void*)h, nullptr, 1536, 768, 768);
  gemm_bt_kernel<1><<<768, 256, 0, stream>>>(h, W2T, nullptr, (void*)m0, (void*)p1, 768, 1536, 1536);
  ln2_kernel<<<8192, 192, 0, stream>>>(m0, p1, x, b2, g2, be2, out);
}